// Round 1
// baseline (239.697 us; speedup 1.0000x reference)
//
#include <hip/hip_runtime.h>

// LocallyConnected2d: out[i,j] = sum_{kh,kw} x[i+kh, j+kw] * W[i,j,kh,kw]
// x: (450,450) f32, W: (436,436,15,15) f32, out: (436,436) f32.
// Memory-bound on the single streaming pass over W (~171 MB).
// Strategy: one 64-lane wave per output; W[i,j,:] is 225 contiguous floats,
// so lane l reads p = l + 64*t (t=0..3, last predicated) -> perfectly
// coalesced 256B wave loads, 100% cache-line utilization. x (810 KB) stays
// hot in L1/L2 with ~225x reuse. Shuffle-reduce across the wave.

constexpr int IN_H = 450, IN_W = 450;
constexpr int KH = 15, KW = 15;
constexpr int OH = 436, OW = 436;
constexpr int NOUT = OH * OW;   // 190096
constexpr int KSIZE = KH * KW;  // 225
constexpr int WAVES_PER_BLOCK = 4;

__global__ __launch_bounds__(256)
void lc2d_wave_per_out(const float* __restrict__ x,
                       const float* __restrict__ W,
                       float* __restrict__ out) {
    const int lane = threadIdx.x & 63;
    const int wave = threadIdx.x >> 6;
    const int oidx = blockIdx.x * WAVES_PER_BLOCK + wave;
    if (oidx >= NOUT) return;

    const int oi = oidx / OW;
    const int oj = oidx - oi * OW;

    const float* __restrict__ wbase = W + (size_t)oidx * KSIZE;
    const float* __restrict__ xbase = x + oi * IN_W + oj;

    float sum = 0.0f;
#pragma unroll
    for (int t = 0; t < 4; ++t) {
        const int p = lane + t * 64;
        if (p < KSIZE) {  // only the t=3 iteration is partially masked
            const int kh = p / KW;        // p < 225, compiler emits magic-mul
            const int kw = p - kh * KW;
            sum += wbase[p] * xbase[kh * IN_W + kw];
        }
    }

    // 64-lane wave reduction
#pragma unroll
    for (int off = 32; off > 0; off >>= 1)
        sum += __shfl_down(sum, off, 64);

    if (lane == 0) out[oidx] = sum;
}

extern "C" void kernel_launch(void* const* d_in, const int* in_sizes, int n_in,
                              void* d_out, int out_size, void* d_ws, size_t ws_size,
                              hipStream_t stream) {
    const float* x = (const float*)d_in[0];  // (450,450)
    const float* W = (const float*)d_in[1];  // (436,436,15,15)
    float* out = (float*)d_out;              // (436,436)

    const int nblocks = (NOUT + WAVES_PER_BLOCK - 1) / WAVES_PER_BLOCK;  // 47524
    lc2d_wave_per_out<<<nblocks, 64 * WAVES_PER_BLOCK, 0, stream>>>(x, W, out);
}